// Round 10
// baseline (1204.887 us; speedup 1.0000x reference)
//
#include <hip/hip_runtime.h>
#include <math.h>

#define NB 262144
#define ND 128
#define NL 8
#define TOT (NL*16)

typedef __bf16 bf16x8 __attribute__((ext_vector_type(8)));
typedef float  f32x4  __attribute__((ext_vector_type(4)));

union BFP { unsigned int u; __bf16 h[2]; unsigned short s[2]; };
union F4  { float4 f; float a[4]; };

__device__ __forceinline__ float sigm(float x){ return 1.0f/(1.0f + __expf(-x)); }
__device__ __forceinline__ float tanhfast(float x){
  float t = __expf(-2.0f*fabsf(x));
  return copysignf((1.0f - t)/(1.0f + t), x);
}
// row r lives in lanes {r, r+16, r+32, r+48}
__device__ __forceinline__ float redrow(float v){
  v += __shfl_xor(v, 16);
  v += __shfl_xor(v, 32);
  return v;
}
__device__ __forceinline__ unsigned int pk2(float a, float b){
  BFP x; x.h[0]=(__bf16)a; x.h[1]=(__bf16)b; return x.u;
}
__device__ __forceinline__ float ubf(unsigned int u, int hi){
  BFP x; x.u = u; return (float)x.h[hi];
}
__device__ __forceinline__ void gload16(const void* g, void* s){
  __builtin_amdgcn_global_load_lds((const __attribute__((address_space(1))) unsigned int*)g,
                                   (__attribute__((address_space(3))) unsigned int*)s,
                                   16, 0, 0);
}

// ---- prep 1: repack Wg/Wp into bf16 A-operand fragment order (r9 verbatim) ----
// dst: [(l*2+mat)][kf(8)][cf(8)][lane(64)] x 16B ; mat 0 = Wg, 1 = Wp
__global__ void repack_w(const float* __restrict__ Wp, const float* __restrict__ Wg,
                         uint4* __restrict__ dst){
  int t = blockIdx.x*256 + threadIdx.x;
  int lane = t & 63;
  int frag = t >> 6;
  int cf = frag & 7, kf = (frag >> 3) & 7, mat = (frag >> 6) & 1, l = frag >> 7;
  const float* W = mat ? Wp : Wg;
  int k = kf*32 + (lane >> 4)*8;
  int n = cf*16 + (lane & 15);
  const float* src = W + (l*256 + k)*ND + n;
  bf16x8 v;
#pragma unroll
  for (int j=0;j<8;++j) v[j] = (__bf16)src[j*ND];
  dst[((l*2 + mat)*64 + kf*8 + cf)*64 + lane] = __builtin_bit_cast(uint4, v);
}

// ---- prep 2: pdot[l][row] = previous[row] . Ws_l[128:256] + bs_l ----
__global__ void prevdot_k(const float* __restrict__ previous, const float* __restrict__ Ws,
                          const float* __restrict__ bs, float* __restrict__ pdot){
  int t = blockIdx.x*256 + threadIdx.x;
  int row = t >> 4, g = t & 15;
  const float* p = previous + (size_t)row*ND + g*8;
  float4 a = *(const float4*)p;
  float4 b = *(const float4*)(p+4);
#pragma unroll
  for (int l=0;l<NL;++l){
    const float* w = Ws + l*256 + 128 + g*8;
    float s = a.x*w[0] + a.y*w[1] + a.z*w[2] + a.w*w[3]
            + b.x*w[4] + b.y*w[5] + b.z*w[6] + b.w*w[7];
    s += __shfl_xor(s,1); s += __shfl_xor(s,2); s += __shfl_xor(s,4); s += __shfl_xor(s,8);
    if (g==0) pdot[(size_t)l*NB + row] = s + bs[l];
  }
}

// ---- main fused kernel: 512 threads = 8 waves x 16 rows ----
// r9 math verbatim; new schedule: counted-vmcnt 3-buffer weight pipeline
// (raw s_barrier, never drain vmcnt mid-loop), all loop constants in LDS,
// prev half of joined kept in registers (tile is cur-only 32KB).
__global__ __launch_bounds__(512)
void fused_k(const float* __restrict__ signal, const float* __restrict__ previous,
             const float* __restrict__ bp, const float* __restrict__ bg,
             const float* __restrict__ Ws, const float* __restrict__ gamma,
             const float* __restrict__ beta,
             const uint4* __restrict__ wpk, const float* __restrict__ pdot,
             float* __restrict__ out)
{
  __shared__ unsigned short tile[128*128];   // 32KB cur-only [row][feat], XOR-swizzled
  __shared__ uint4 wbuf[3][512];             // 24KB: 3 x 8KB weight stages
  __shared__ float cst[5*1024];              // 20KB: bg|bp|gamma|beta|Ws0 as [arr][l*128+n]
  __shared__ float pdl[1024];                // 4KB: pdot [l][local row]

  const int tid  = threadIdx.x;
  const int w    = tid >> 6;
  const int lane = tid & 63;
  const int llo  = lane & 15;
  const int lhi  = lane >> 4;
  const int rbase = w * 16;
  const int row0  = blockIdx.x * 128;
  const int swz   = (llo & 7) << 4;

  auto gstage = [&](int s, int b){
    gload16((const char*)wpk + (size_t)s*8192 + tid*16, (char*)&wbuf[b][0] + tid*16);
  };

  // ---- prologue: constants -> LDS; signal -> tile; previous -> registers ----
#pragma unroll
  for (int i = tid; i < 1024; i += 512){
    cst[i]        = bg[i];
    cst[1024 + i] = bp[i];
    cst[2048 + i] = gamma[i];
    cst[3072 + i] = beta[i];
    cst[4096 + i] = Ws[(i >> 7)*256 + (i & 127)];
    pdl[i]        = pdot[(size_t)(i >> 7)*NB + row0 + (i & 127)];
  }

  unsigned int gstash[16];
  float accv[8][4];
  f32x4 pacc[8];
  bf16x8 prevB[4];            // prev joined-half fragments, persistent
  float active, depth, smass, gsum, dsum, asum;

  {
    int rl = rbase + llo;
    int rowg = row0 + rl;
#pragma unroll
    for (int cf=0; cf<8; ++cf){
      F4 v; v.f = *(const float4*)&signal[(size_t)rowg*ND + 16*cf + 4*lhi];
      unsigned p0 = pk2(v.a[0], v.a[1]);
      unsigned p1 = pk2(v.a[2], v.a[3]);
      char* dst = (char*)tile + rl*256 + ((32*cf + 8*lhi) ^ swz);
      *(unsigned long long*)dst = (unsigned long long)p0 | ((unsigned long long)p1 << 32);
      pacc[cf] = (f32x4){0.f,0.f,0.f,0.f};
#pragma unroll
      for (int j=0;j<4;++j) accv[cf][j] = 0.f;
    }
#pragma unroll
    for (int kfp=0; kfp<4; ++kfp){
      const float* p = previous + (size_t)rowg*ND + kfp*32 + lhi*8;
      F4 a; a.f = *(const float4*)p;
      F4 b; b.f = *(const float4*)(p+4);
      uint4 pv;
      pv.x = pk2(a.a[0], a.a[1]);
      pv.y = pk2(a.a[2], a.a[3]);
      pv.z = pk2(b.a[0], b.a[1]);
      pv.w = pk2(b.a[2], b.a[3]);
      prevB[kfp] = __builtin_bit_cast(bf16x8, pv);
    }
    active=1.f; depth=0.f; smass=0.f; gsum=0.f; dsum=0.f; asum=0.f;
  }
  __syncthreads();                           // consts + tile visible to all
  gstage(0, 0);
  gstage(1, 1);

  auto compute = [&](int s, int buf){
    int kf = s & 7;
    bf16x8 xf;
    if (kf < 4){
      int off = (64*kf + 16*lhi) ^ swz;
      xf = __builtin_bit_cast(bf16x8,
          *(const uint4*)((const char*)tile + (rbase + llo)*256 + off));
    } else {
      xf = prevB[kf-4];
    }
    const uint4* wb = &wbuf[buf][lane];
#pragma unroll
    for (int cf=0; cf<8; ++cf){
      bf16x8 wf = __builtin_bit_cast(bf16x8, wb[cf*64]);
      pacc[cf] = __builtin_amdgcn_mfma_f32_16x16x32_bf16(wf, xf, pacc[cf], 0,0,0);
    }
  };

  auto gate_epi = [&](int lev){
    float gp = 0.f;
#pragma unroll
    for (int cf=0; cf<8; ++cf){
      F4 bgv; bgv.f = *(const float4*)&cst[lev*128 + 16*cf + 4*lhi];
      float g0 = sigm(pacc[cf][0] + bgv.a[0]);
      float g1 = sigm(pacc[cf][1] + bgv.a[1]);
      float g2 = sigm(pacc[cf][2] + bgv.a[2]);
      float g3 = sigm(pacc[cf][3] + bgv.a[3]);
      gp += g0 + g1 + g2 + g3;
      gstash[2*cf]   = pk2(g0, g1);
      gstash[2*cf+1] = pk2(g2, g3);
      pacc[cf] = (f32x4){0.f,0.f,0.f,0.f};
    }
    gsum += redrow(gp) * (1.0f/ND);
  };

  auto cand_epi = [&](int lev, bool wr){
    int rl = rbase + llo;
    char* cbase = (char*)tile + rl*256;
    float s1 = 0.f, s2 = 0.f;
#pragma unroll
    for (int cf=0; cf<8; ++cf){
      F4 bpv; bpv.f = *(const float4*)&cst[1024 + lev*128 + 16*cf + 4*lhi];
      unsigned long long cw = *(const unsigned long long*)(cbase + ((32*cf + 8*lhi) ^ swz));
      unsigned c0 = (unsigned)cw, c1 = (unsigned)(cw >> 32);
#pragma unroll
      for (int j=0;j<4;++j){
        float cand = tanhfast(pacc[cf][j] + bpv.a[j]);
        float cc = ubf(j<2 ? c0 : c1, j&1);
        float gt = ubf(gstash[2*cf + (j>>1)], j&1);
        float x = cc + gt*(cand - cc);
        pacc[cf][j] = x;
        s1 += x; s2 += x*x;
      }
    }
    s1 = redrow(s1); s2 = redrow(s2);
    float mu  = s1*(1.0f/ND);
    float inv = rsqrtf(s2*(1.0f/ND) - mu*mu + 1e-5f);
    float dp = 0.f, ap = 0.f;
#pragma unroll
    for (int cf=0; cf<8; ++cf){
      F4 gm; gm.f = *(const float4*)&cst[2048 + lev*128 + 16*cf + 4*lhi];
      F4 bt; bt.f = *(const float4*)&cst[3072 + lev*128 + 16*cf + 4*lhi];
      F4 wv; wv.f = *(const float4*)&cst[4096 + lev*128 + 16*cf + 4*lhi];
      unsigned long long cw = *(const unsigned long long*)(cbase + ((32*cf + 8*lhi) ^ swz));
      unsigned c0 = (unsigned)cw, c1 = (unsigned)(cw >> 32);
#pragma unroll
      for (int j=0;j<4;++j){
        float un = (pacc[cf][j] - mu)*inv*gm.a[j] + bt.a[j];
        float cc = ubf(j<2 ? c0 : c1, j&1);
        float df = un - cc;
        dp += df*df;
        ap += un*wv.a[j];
        pacc[cf][j] = un;
      }
    }
    dp = redrow(dp); ap = redrow(ap);
    float adq = sigm(ap + pdl[lev*128 + rl]);
    float sp  = sigm((adq - 0.6f)*10.0f);
    float sm  = active*sp;
    asum += adq;
    dsum += sqrtf(dp);
    depth += sm * (float)(lev+1);
    smass += sm;
    active *= (1.0f - sp);
#pragma unroll
    for (int cf=0; cf<8; ++cf){
#pragma unroll
      for (int j=0;j<4;++j) accv[cf][j] += sm * pacc[cf][j];
      if (wr){
        unsigned p0 = pk2(pacc[cf][0], pacc[cf][1]);
        unsigned p1 = pk2(pacc[cf][2], pacc[cf][3]);
        char* dst = cbase + ((32*cf + 8*lhi) ^ swz);
        *(unsigned long long*)dst = (unsigned long long)p0 | ((unsigned long long)p1 << 32);
        pacc[cf] = (f32x4){0.f,0.f,0.f,0.f};   // must be zero for next gate GEMM
      }
    }
    if (wr){
      asm volatile("s_waitcnt lgkmcnt(0)" ::: "memory");
      __builtin_amdgcn_sched_barrier(0);
    }
  };

  // ---- main loop: counted-vmcnt pipeline, 2 weight stages in flight ----
  int bufc = 0;  // s % 3
#pragma unroll 1
  for (int s=0; s<TOT; ++s){
    if (s < TOT-1) asm volatile("s_waitcnt vmcnt(1)" ::: "memory");   // stage s resident
    else           asm volatile("s_waitcnt vmcnt(0)" ::: "memory");
    __builtin_amdgcn_s_barrier();
    __builtin_amdgcn_sched_barrier(0);
    if (s+2 < TOT){
      int b2 = bufc + 2; if (b2 >= 3) b2 -= 3;
      gstage(s+2, b2);                       // flies across the next 2 stages
    }
    int q = s & 15, l = s >> 4;
    if (q == 8) gate_epi(l);
    else if (q == 0 && l > 0) cand_epi(l-1, true);
    compute(s, bufc);
    bufc = (bufc == 2) ? 0 : bufc + 1;
  }
  cand_epi(NL-1, false);                     // pacc holds final updated vector

  // ---- outputs ----
  {
    int rowg = row0 + rbase + llo;
#pragma unroll
    for (int cf=0; cf<8; ++cf){
      F4 o;
#pragma unroll
      for (int j=0;j<4;++j)
        o.a[j] = accv[cf][j] + active*pacc[cf][j];
      *(float4*)&out[(size_t)rowg*ND + 16*cf + 4*lhi] = o.f;
    }
    if (lhi == 0){
      const size_t BD = (size_t)NB*ND;
      out[BD + rowg]                = gsum*(1.0f/NL);
      out[BD + NB + rowg]           = dsum*(1.0f/NL);
      out[BD + 2*(size_t)NB + rowg] = depth + active*(float)NL;
      out[BD + 3*(size_t)NB + rowg] = smass;
      out[BD + 4*(size_t)NB + rowg] = asum*(1.0f/NL);
    }
  }
}

extern "C" void kernel_launch(void* const* d_in, const int* in_sizes, int n_in,
                              void* d_out, int out_size, void* d_ws, size_t ws_size,
                              hipStream_t stream){
  const float* signal   = (const float*)d_in[0];
  const float* previous = (const float*)d_in[1];
  const float* Wp    = (const float*)d_in[2];
  const float* bp    = (const float*)d_in[3];
  const float* Wg    = (const float*)d_in[4];
  const float* bg    = (const float*)d_in[5];
  const float* Ws    = (const float*)d_in[6];
  const float* bs    = (const float*)d_in[7];
  const float* gamma = (const float*)d_in[8];
  const float* beta  = (const float*)d_in[9];

  uint4* wpk  = (uint4*)d_ws;                                   // 1 MB packed weights
  float* pdot = (float*)((char*)d_ws + (size_t)NL*2*65536);     // 8 MB prevdot [l][row]

  repack_w<<<256, 256, 0, stream>>>(Wp, Wg, wpk);
  prevdot_k<<<NB/16, 256, 0, stream>>>(previous, Ws, bs, pdot);
  fused_k<<<NB/128, 512, 0, stream>>>(signal, previous, bp, bg, Ws, gamma, beta,
                                      wpk, pdot, (float*)d_out);
}